// Round 1
// baseline (1560.255 us; speedup 1.0000x reference)
//
#include <hip/hip_runtime.h>

// ---------------- sizes ----------------
// B=8, C=64, H=W=96, S=9216, NH=4 (dil=1,2,4,8), NL=8, hid=16
// KV rows per (i,b): 256 (0..127 = K via k_w, 128..255 = V via v_w)
// conv GEMM per (i,b): [256 o] x [576 k = tap*64+c] x [9216 s]

// ---------------- workspace layout (bytes) ----------------
#define WS_CENPAD 0UL           // f32 [8][64][112][112]      = 25,690,112
#define WS_W      25690112UL    // f32 [4][576][256]          =  2,359,296
#define WS_Q      28049408UL    // f32 [4][8][16][9216]       = 18,874,368
#define WS_KV     46923776UL    // bf16 [4][8][256][9216]     = 150,994,944
#define WS_SPART  197918720UL   // f32 [288][2048]            =  2,359,296
#define WS_KKP    200278016UL   // f32 [288][128]             =    147,456
#define WS_QQP    200425472UL   // f32 [288][16]              =     18,432
#define WS_ATTN   200443904UL   // f32 [32][128][16]          =    262,144
#define WS_OUT    200706048UL   // f32 [8][64][9216]          = 18,874,368
#define WS_BN     219580416UL   // f32 [128]
// total ~209.4 MB

__device__ __forceinline__ float bf2f(unsigned short h){ return __uint_as_float(((unsigned int)h)<<16); }
__device__ __forceinline__ float bflo(unsigned int u){ return __uint_as_float(u<<16); }
__device__ __forceinline__ float bfhi(unsigned int u){ return __uint_as_float(u & 0xffff0000u); }
__device__ __forceinline__ unsigned short f2bf(float f){
  unsigned int u = __float_as_uint(f);
  return (unsigned short)((u + 0x7fffu + ((u>>16)&1u)) >> 16);
}

// ---- pad: cen [8,64,96,96] f32 -> cenpad [8,64,112,112] f32 (8-halo zeros)
__global__ __launch_bounds__(256) void pad_kernel(const float* __restrict__ cen, float* __restrict__ cenpad){
  int idx = blockIdx.x*256 + threadIdx.x;  // exactly 6,422,528 threads
  int px = idx % 112; int t = idx / 112; int py = t % 112; int bc = t / 112;
  int y = py - 8, x = px - 8;
  float v = 0.f;
  if (y >= 0 && y < 96 && x >= 0 && x < 96) v = cen[(size_t)bc*9216 + y*96 + x];
  cenpad[idx] = v;
}

// ---- prep: build conv weights W[i][t*64+c][o], o<128 from k_w, o>=128 from v_w
__global__ __launch_bounds__(256) void prep_kernel(const float* __restrict__ sumw,
    const float* __restrict__ kw, const float* __restrict__ vw, float* __restrict__ Wf){
  int idx = blockIdx.x*256 + threadIdx.x;  // exactly 589,824
  int o = idx & 255; int r = idx >> 8; int c = r & 63; r >>= 6; int t = r % 9; int i = r / 9;
  float l0 = sumw[(i*64 + c)*2 + 0], l1 = sumw[(i*64 + c)*2 + 1];
  float m = fmaxf(l0, l1);
  float e0 = expf(l0 - m), e1 = expf(l1 - m);
  float inv = 1.f/(e0 + e1);
  float sw0 = e0*inv, sw1 = e1*inv;
  const float* wsrc = (o < 128) ? (kw + ((size_t)i*128 + o)*512 + c)
                                : (vw + ((size_t)i*128 + (o-128))*512 + c);
  float A = 0.f;
  #pragma unroll
  for (int j = 0; j < 8; ++j) A += wsrc[j*64];
  float val;
  if (t == 4) {
    val = A;  // center tap: all mixed kernels have weight 1 at center (sw0+sw1=1)
  } else {
    // tap (ky,kx)=t -> which base kernel has its -1 there
    const int tmap[9] = {0,1,2,7,0,3,6,5,4};
    int j = tmap[t];
    val = -(wsrc[j*64]*sw0 + A*sw1*0.125f);
  }
  Wf[((size_t)i*576 + t*64 + c)*256 + o] = val;
}

// ---- Q projection: qbuf[i][b][oq][s] f32 = q_w[i] @ cen
__global__ __launch_bounds__(256) void qproj_kernel(const float* __restrict__ cen,
    const float* __restrict__ qw, float* __restrict__ qbuf){
  __shared__ float WT[64][16];  // [c][oq]
  int tid = threadIdx.x;
  int st = blockIdx.x; int ib = blockIdx.y; int i = ib >> 3, b = ib & 7;
  #pragma unroll
  for (int e = 0; e < 4; ++e) {
    int f = e*256 + tid; int c = f >> 4, o = f & 15;
    WT[c][o] = qw[(size_t)i*1024 + o*64 + c];
  }
  __syncthreads();
  int s = st*256 + tid;
  float acc[16];
  #pragma unroll
  for (int o = 0; o < 16; ++o) acc[o] = 0.f;
  const float* cb = cen + (size_t)b*64*9216 + s;
  for (int c = 0; c < 64; ++c) {
    float xv = cb[(size_t)c*9216];
    #pragma unroll
    for (int o4 = 0; o4 < 4; ++o4) {
      float4 w = *(const float4*)&WT[c][o4*4];
      acc[o4*4+0] = fmaf(w.x, xv, acc[o4*4+0]);
      acc[o4*4+1] = fmaf(w.y, xv, acc[o4*4+1]);
      acc[o4*4+2] = fmaf(w.z, xv, acc[o4*4+2]);
      acc[o4*4+3] = fmaf(w.w, xv, acc[o4*4+3]);
    }
  }
  float* qb = qbuf + ((size_t)(i*8 + b)*16)*9216 + s;
  #pragma unroll
  for (int o = 0; o < 16; ++o) qb[(size_t)o*9216] = acc[o];
}

// ---- conv K/V: implicit GEMM [256 x 576] @ [576 x 9216] per (i,b), write bf16
// block: 64 o-rows x 256 s-cols; thread (ty,tx): 4 o x (4x strided-4) s
__global__ __launch_bounds__(256) void conv_kv_kernel(const float* __restrict__ cenpad,
    const float* __restrict__ Wf, unsigned short* __restrict__ KV){
  __shared__ float Wl[32][64];    // [kk][o]
  __shared__ float Xl[32][256];   // [kk][s]
  const int tid = threadIdx.x;
  const int st = blockIdx.x, oc = blockIdx.y, ib = blockIdx.z;
  const int i = ib >> 3, b = ib & 7;
  const int dil = 1 << i;          // SHIFTS = 1,2,4,8
  const int s0 = st * 256, o0 = oc * 64;
  const int ty = tid >> 4, tx = tid & 15;
  const int s = s0 + tid;
  const int y = s / 96;
  const int x = s - y*96;
  const float* cb = cenpad + (size_t)b * 802816;
  const float* Wbase = Wf + (size_t)i * 147456 + o0;
  float acc[4][16];
  #pragma unroll
  for (int r = 0; r < 4; ++r)
    #pragma unroll
    for (int e = 0; e < 16; ++e) acc[r][e] = 0.f;

  for (int kc = 0; kc < 18; ++kc) {
    // stage W chunk [32][64]
    #pragma unroll
    for (int e = 0; e < 8; ++e) {
      int f = e*256 + tid;
      ((float*)Wl)[f] = Wbase[(size_t)kc*8192 + (size_t)(f >> 6)*256 + (f & 63)];
    }
    // stage X chunk: k = kc*32+e -> tap t = kc>>1 (chunk-constant), c = (kc&1)*32 + e
    {
      int t = kc >> 1;
      int c0 = (kc & 1) * 32;
      int dy = (t/3 - 1) * dil;
      int dx = (t - (t/3)*3 - 1) * dil;
      const float* p = cb + (size_t)c0*12544 + (size_t)(y + 8 + dy)*112 + (x + 8 + dx);
      #pragma unroll
      for (int e = 0; e < 32; ++e) Xl[e][tid] = p[(size_t)e*12544];
    }
    __syncthreads();
    #pragma unroll 4
    for (int kk = 0; kk < 32; ++kk) {
      float4 w = *(const float4*)&Wl[kk][ty*4];
      const float* xr = &Xl[kk][tx*4];
      float4 x0 = *(const float4*)(xr);
      float4 x1 = *(const float4*)(xr + 64);
      float4 x2 = *(const float4*)(xr + 128);
      float4 x3 = *(const float4*)(xr + 192);
      float wv[4] = {w.x, w.y, w.z, w.w};
      float xv[16] = {x0.x,x0.y,x0.z,x0.w, x1.x,x1.y,x1.z,x1.w,
                      x2.x,x2.y,x2.z,x2.w, x3.x,x3.y,x3.z,x3.w};
      #pragma unroll
      for (int r = 0; r < 4; ++r)
        #pragma unroll
        for (int e = 0; e < 16; ++e) acc[r][e] = fmaf(wv[r], xv[e], acc[r][e]);
    }
    __syncthreads();
  }
  unsigned short* outp = KV + ((size_t)((i*8 + b)*256 + o0 + ty*4))*9216 + s0 + tx*4;
  #pragma unroll
  for (int r = 0; r < 4; ++r) {
    #pragma unroll
    for (int e4 = 0; e4 < 4; ++e4) {
      uint2 pk;
      pk.x = (unsigned int)f2bf(acc[r][e4*4+0]) | ((unsigned int)f2bf(acc[r][e4*4+1]) << 16);
      pk.y = (unsigned int)f2bf(acc[r][e4*4+2]) | ((unsigned int)f2bf(acc[r][e4*4+3]) << 16);
      *(uint2*)(outp + (size_t)r*9216 + e4*64) = pk;
    }
  }
}

// ---- scores: per (b,hh,chunk of 1024 s): partial 16x128 dots + row sumsq
__global__ __launch_bounds__(256) void scores_kernel(const unsigned short* __restrict__ KV,
    const float* __restrict__ qbuf, float* __restrict__ spart,
    float* __restrict__ kkpart, float* __restrict__ qqpart){
  __shared__ float Klds[64][128];  // [s][kr]
  __shared__ float Qlds[16][64];   // [qr][s]
  const int tid = threadIdx.x;
  const int chunk = blockIdx.x, hh = blockIdx.y, b = blockIdx.z;
  const int kr = tid & 127, qrg = (tid >> 7) * 8;
  float acc[8] = {0,0,0,0,0,0,0,0};
  float kacc = 0.f, qacc = 0.f;
  const int skr = tid >> 2;
  const int sq16 = (tid & 3) * 16;
  const int qrow = tid >> 4, qoff = (tid & 15) * 4;
  const float* qsrc = qbuf + ((size_t)(((qrow & 3)*8 + b)*16 + hh*4 + (qrow >> 2)))*9216;

  for (int sc = 0; sc < 16; ++sc) {
    int sb = chunk*1024 + sc*64;
    #pragma unroll
    for (int p = 0; p < 2; ++p) {
      int krr = p*64 + skr;
      int ii = krr & 3, oo = hh*32 + (krr >> 2);
      const unsigned short* src = KV + ((size_t)((ii*8 + b)*256 + oo))*9216 + sb + sq16;
      uint4 u0 = *(const uint4*)src;
      uint4 u1 = *(const uint4*)(src + 8);
      Klds[sq16+ 0][krr] = bflo(u0.x); Klds[sq16+ 1][krr] = bfhi(u0.x);
      Klds[sq16+ 2][krr] = bflo(u0.y); Klds[sq16+ 3][krr] = bfhi(u0.y);
      Klds[sq16+ 4][krr] = bflo(u0.z); Klds[sq16+ 5][krr] = bfhi(u0.z);
      Klds[sq16+ 6][krr] = bflo(u0.w); Klds[sq16+ 7][krr] = bfhi(u0.w);
      Klds[sq16+ 8][krr] = bflo(u1.x); Klds[sq16+ 9][krr] = bfhi(u1.x);
      Klds[sq16+10][krr] = bflo(u1.y); Klds[sq16+11][krr] = bfhi(u1.y);
      Klds[sq16+12][krr] = bflo(u1.z); Klds[sq16+13][krr] = bfhi(u1.z);
      Klds[sq16+14][krr] = bflo(u1.w); Klds[sq16+15][krr] = bfhi(u1.w);
    }
    *(float4*)&Qlds[qrow][qoff] = *(const float4*)(qsrc + sb + qoff);
    __syncthreads();
    #pragma unroll 4
    for (int s4 = 0; s4 < 16; ++s4) {
      float k0 = Klds[s4*4+0][kr], k1 = Klds[s4*4+1][kr];
      float k2 = Klds[s4*4+2][kr], k3 = Klds[s4*4+3][kr];
      if (tid < 128) kacc += k0*k0 + k1*k1 + k2*k2 + k3*k3;
      #pragma unroll
      for (int q = 0; q < 8; ++q) {
        float4 qv = *(const float4*)&Qlds[qrg + q][s4*4];
        acc[q] += k0*qv.x + k1*qv.y + k2*qv.z + k3*qv.w;
      }
      if (tid >= 128 && tid < 144) {
        float4 qv = *(const float4*)&Qlds[tid & 15][s4*4];
        qacc += qv.x*qv.x + qv.y*qv.y + qv.z*qv.z + qv.w*qv.w;
      }
    }
    __syncthreads();
  }
  int pb = (b*4 + hh)*9 + chunk;
  #pragma unroll
  for (int q = 0; q < 8; ++q) spart[(size_t)pb*2048 + (qrg+q)*128 + kr] = acc[q];
  if (tid < 128) kkpart[(size_t)pb*128 + tid] = kacc;
  if (tid >= 128 && tid < 144) qqpart[(size_t)pb*16 + (tid - 128)] = qacc;
}

// ---- softmax: reduce partials, l2-normalize scale, instance-norm, row softmax -> attnT[kr][qr]
__global__ __launch_bounds__(256) void softmax_kernel(const float* __restrict__ spart,
    const float* __restrict__ kkpart, const float* __restrict__ qqpart, float* __restrict__ attnT){
  const int pb = blockIdx.x, tid = threadIdx.x;
  const int qr = tid >> 4, g = tid & 15;
  __shared__ float kkl[128];
  __shared__ float qql[16];
  __shared__ float red[8];
  __shared__ float stats[2];
  float sv[8] = {0,0,0,0,0,0,0,0};
  for (int ch = 0; ch < 9; ++ch) {
    const float* p = spart + ((size_t)(pb*9 + ch))*2048 + qr*128 + g*8;
    #pragma unroll
    for (int e = 0; e < 8; ++e) sv[e] += p[e];
  }
  if (tid < 128) { float ssum = 0.f; for (int ch = 0; ch < 9; ++ch) ssum += kkpart[(size_t)(pb*9+ch)*128 + tid]; kkl[tid] = ssum; }
  if (tid < 16)  { float ssum = 0.f; for (int ch = 0; ch < 9; ++ch) ssum += qqpart[(size_t)(pb*9+ch)*16 + tid]; qql[tid] = ssum; }
  __syncthreads();
  float qn = fmaxf(sqrtf(qql[qr]), 1e-12f);
  float lsum = 0.f, lsq = 0.f;
  #pragma unroll
  for (int e = 0; e < 8; ++e) {
    float kn = fmaxf(sqrtf(kkl[g*8+e]), 1e-12f);
    float v = sv[e] / (qn * kn * 96.0f);
    sv[e] = v; lsum += v; lsq += v*v;
  }
  #pragma unroll
  for (int m = 1; m <= 32; m <<= 1) { lsum += __shfl_xor(lsum, m); lsq += __shfl_xor(lsq, m); }
  if ((tid & 63) == 0) { red[tid >> 6] = lsum; red[4 + (tid >> 6)] = lsq; }
  __syncthreads();
  if (tid == 0) {
    float ts = red[0]+red[1]+red[2]+red[3];
    float tq = red[4]+red[5]+red[6]+red[7];
    float mean = ts / 2048.0f;
    float var = tq / 2048.0f - mean*mean;
    stats[0] = mean; stats[1] = rsqrtf(var + 1e-5f);
  }
  __syncthreads();
  float mean = stats[0], inv = stats[1];
  float mx = -1e30f;
  #pragma unroll
  for (int e = 0; e < 8; ++e) { sv[e] = (sv[e] - mean) * inv; mx = fmaxf(mx, sv[e]); }
  #pragma unroll
  for (int m = 1; m <= 8; m <<= 1) mx = fmaxf(mx, __shfl_xor(mx, m));
  float es = 0.f;
  #pragma unroll
  for (int e = 0; e < 8; ++e) { sv[e] = expf(sv[e] - mx); es += sv[e]; }
  #pragma unroll
  for (int m = 1; m <= 8; m <<= 1) es += __shfl_xor(es, m);
  float rinv = 1.0f / es;
  #pragma unroll
  for (int e = 0; e < 8; ++e) attnT[(size_t)pb*2048 + (g*8+e)*16 + qr] = sv[e] * rinv;
}

// ---- PV: out[b][hh*16+qr][s] = sum_kr attn * V
__global__ __launch_bounds__(256) void pv_kernel(const unsigned short* __restrict__ KV,
    const float* __restrict__ attnT, float* __restrict__ outbuf){
  __shared__ float at[128][16];
  int tid = threadIdx.x;
  int st = blockIdx.x, hh = blockIdx.y, b = blockIdx.z;
  const float* ap = attnT + ((size_t)(b*4 + hh))*2048;
  #pragma unroll
  for (int e = 0; e < 8; ++e) ((float*)at)[e*256 + tid] = ap[e*256 + tid];
  __syncthreads();
  int sbase = st*1024 + tid*4;
  float acc[16][4];
  #pragma unroll
  for (int q = 0; q < 16; ++q)
    #pragma unroll
    for (int p = 0; p < 4; ++p) acc[q][p] = 0.f;
  #pragma unroll 2
  for (int kr = 0; kr < 128; ++kr) {
    int ii = kr & 3, oo = 128 + hh*32 + (kr >> 2);
    const unsigned short* vp = KV + ((size_t)((ii*8 + b)*256 + oo))*9216 + sbase;
    uint2 u = *(const uint2*)vp;
    float v0 = bflo(u.x), v1 = bfhi(u.x), v2 = bflo(u.y), v3 = bfhi(u.y);
    #pragma unroll
    for (int q4 = 0; q4 < 4; ++q4) {
      float4 a = *(const float4*)&at[kr][q4*4];
      float av[4] = {a.x, a.y, a.z, a.w};
      #pragma unroll
      for (int j = 0; j < 4; ++j) {
        acc[q4*4+j][0] = fmaf(av[j], v0, acc[q4*4+j][0]);
        acc[q4*4+j][1] = fmaf(av[j], v1, acc[q4*4+j][1]);
        acc[q4*4+j][2] = fmaf(av[j], v2, acc[q4*4+j][2]);
        acc[q4*4+j][3] = fmaf(av[j], v3, acc[q4*4+j][3]);
      }
    }
  }
  float* ob = outbuf + ((size_t)(b*64 + hh*16))*9216 + sbase;
  #pragma unroll
  for (int q = 0; q < 16; ++q) {
    float4 w = make_float4(acc[q][0], acc[q][1], acc[q][2], acc[q][3]);
    *(float4*)(ob + (size_t)q*9216) = w;
  }
}

// ---- 1x1 out conv -> d_out (pre-BN)
__global__ __launch_bounds__(256) void outconv_kernel(const float* __restrict__ outbuf,
    const float* __restrict__ ow, float* __restrict__ dout){
  __shared__ float WT[64][64];  // [c][o]
  int tid = threadIdx.x; int st = blockIdx.x; int b = blockIdx.y;
  #pragma unroll
  for (int e = 0; e < 16; ++e) {
    int f = e*256 + tid; int c = f >> 6, o = f & 63;
    WT[c][o] = ow[o*64 + c];
  }
  __syncthreads();
  int s = st*256 + tid;
  float acc[64];
  #pragma unroll
  for (int o = 0; o < 64; ++o) acc[o] = 0.f;
  for (int c = 0; c < 64; ++c) {
    float xv = outbuf[((size_t)(b*64 + c))*9216 + s];
    #pragma unroll
    for (int o4 = 0; o4 < 16; ++o4) {
      float4 w = *(const float4*)&WT[c][o4*4];
      acc[o4*4+0] = fmaf(w.x, xv, acc[o4*4+0]);
      acc[o4*4+1] = fmaf(w.y, xv, acc[o4*4+1]);
      acc[o4*4+2] = fmaf(w.z, xv, acc[o4*4+2]);
      acc[o4*4+3] = fmaf(w.w, xv, acc[o4*4+3]);
    }
  }
  #pragma unroll
  for (int o = 0; o < 64; ++o) dout[((size_t)(b*64 + o))*9216 + s] = acc[o];
}

// ---- BN stats per channel over (b, h, w)
__global__ __launch_bounds__(256) void bnstats_kernel(const float* __restrict__ yb, float* __restrict__ bn){
  int o = blockIdx.x; int tid = threadIdx.x;
  float s = 0.f, sq = 0.f;
  for (int idx = tid; idx < 73728; idx += 256) {
    int b = idx / 9216, sp = idx - b*9216;
    float v = yb[((size_t)(b*64 + o))*9216 + sp];
    s += v; sq += v*v;
  }
  #pragma unroll
  for (int m = 1; m <= 32; m <<= 1) { s += __shfl_xor(s, m); sq += __shfl_xor(sq, m); }
  __shared__ float r0[4], r1[4];
  if ((tid & 63) == 0) { r0[tid >> 6] = s; r1[tid >> 6] = sq; }
  __syncthreads();
  if (tid == 0) {
    float ts = r0[0]+r0[1]+r0[2]+r0[3];
    float tq = r1[0]+r1[1]+r1[2]+r1[3];
    float mean = ts / 73728.f;
    float var = tq / 73728.f - mean*mean;
    bn[o] = mean;
    bn[64 + o] = rsqrtf(var + 1e-5f);
  }
}

// ---- BN apply + ReLU (in place on d_out), float4
__global__ __launch_bounds__(256) void bnapply_kernel(float* __restrict__ yb,
    const float* __restrict__ bn, const float* __restrict__ gamma, const float* __restrict__ beta){
  int gid = blockIdx.x*256 + threadIdx.x;  // exactly 1,179,648 float4s
  int o = (gid / 2304) & 63;
  float mean = bn[o], inv = bn[64 + o];
  float g = gamma[o], be = beta[o];
  float4 v = ((const float4*)yb)[gid];
  v.x = fmaxf((v.x - mean)*inv*g + be, 0.f);
  v.y = fmaxf((v.y - mean)*inv*g + be, 0.f);
  v.z = fmaxf((v.z - mean)*inv*g + be, 0.f);
  v.w = fmaxf((v.w - mean)*inv*g + be, 0.f);
  ((float4*)yb)[gid] = v;
}

extern "C" void kernel_launch(void* const* d_in, const int* in_sizes, int n_in,
                              void* d_out, int out_size, void* d_ws, size_t ws_size,
                              hipStream_t stream) {
  const float* cen   = (const float*)d_in[0];
  const float* sumw  = (const float*)d_in[1];
  const float* qw    = (const float*)d_in[2];
  const float* kw    = (const float*)d_in[3];
  const float* vw    = (const float*)d_in[4];
  const float* ow    = (const float*)d_in[5];
  const float* gamma = (const float*)d_in[6];
  const float* beta  = (const float*)d_in[7];

  char* ws = (char*)d_ws;
  float*          cenpad = (float*)(ws + WS_CENPAD);
  float*          Wf     = (float*)(ws + WS_W);
  float*          qbuf   = (float*)(ws + WS_Q);
  unsigned short* KV     = (unsigned short*)(ws + WS_KV);
  float*          spart  = (float*)(ws + WS_SPART);
  float*          kkp    = (float*)(ws + WS_KKP);
  float*          qqp    = (float*)(ws + WS_QQP);
  float*          attnT  = (float*)(ws + WS_ATTN);
  float*          outbuf = (float*)(ws + WS_OUT);
  float*          bn     = (float*)(ws + WS_BN);

  pad_kernel   <<<25088, 256, 0, stream>>>(cen, cenpad);
  prep_kernel  <<<2304, 256, 0, stream>>>(sumw, kw, vw, Wf);
  qproj_kernel <<<dim3(36, 32), 256, 0, stream>>>(cen, qw, qbuf);
  conv_kv_kernel<<<dim3(36, 4, 32), 256, 0, stream>>>(cenpad, Wf, KV);
  scores_kernel<<<dim3(9, 4, 8), 256, 0, stream>>>(KV, qbuf, spart, kkp, qqp);
  softmax_kernel<<<32, 256, 0, stream>>>(spart, kkp, qqp, attnT);
  pv_kernel    <<<dim3(9, 4, 8), 256, 0, stream>>>(KV, attnT, outbuf);
  outconv_kernel<<<dim3(36, 8), 256, 0, stream>>>(outbuf, ow, (float*)d_out);
  bnstats_kernel<<<64, 256, 0, stream>>>((const float*)d_out, bn);
  bnapply_kernel<<<4608, 256, 0, stream>>>((float*)d_out, bn, gamma, beta);
}

// Round 2
// 639.302 us; speedup vs baseline: 2.4406x; 2.4406x over previous
//
#include <hip/hip_runtime.h>
#include <hip/hip_bf16.h>

// ---------------- sizes ----------------
// B=8, C=64, H=W=96, S=9216, NH=4 (dil=1,2,4,8), NL=8, hid=16
// KV rows per (i,b): 256 (0..127 = K via k_w, 128..255 = V via v_w)
// conv GEMM per (i,b): [256 o] x [576 k = tap*64+c] x [9216 s], bf16 MFMA

// ---------------- workspace layout (bytes) ----------------
#define WS_CENPAD 0UL           // f32 [8][64][112][112]      = 25,690,112
#define WS_W      25690112UL    // bf16 [4][18][256][32]      =  1,179,648 (frag-ready)
#define WS_Q      28049408UL    // f32 [4][8][16][9216]       = 18,874,368
#define WS_KV     46923776UL    // bf16 [4][8][256][9216]     = 150,994,944
#define WS_SPART  197918720UL   // f32 [288][2048]            =  2,359,296
#define WS_KKP    200278016UL   // f32 [288][128]             =    147,456
#define WS_QQP    200425472UL   // f32 [288][16]              =     18,432
#define WS_ATTN   200443904UL   // f32 [32][128][16]          =    262,144
#define WS_OUT    200706048UL   // f32 [8][64][9216]          = 18,874,368
#define WS_BN     219580416UL   // f32 [128]

typedef __attribute__((ext_vector_type(8))) short short8;
typedef __attribute__((ext_vector_type(4))) float f32x4;

__device__ __forceinline__ float bflo(unsigned int u){ return __uint_as_float(u<<16); }
__device__ __forceinline__ float bfhi(unsigned int u){ return __uint_as_float(u & 0xffff0000u); }
__device__ __forceinline__ unsigned short f2bf(float f){
  unsigned int u = __float_as_uint(f);
  return (unsigned short)((u + 0x7fffu + ((u>>16)&1u)) >> 16);
}
__device__ __forceinline__ unsigned short fbits(float f){
  __hip_bfloat16 h = __float2bfloat16(f);
  return __builtin_bit_cast(unsigned short, h);
}

// ---- pad: cen [8,64,96,96] f32 -> cenpad [8,64,112,112] f32 (8-halo zeros)
__global__ __launch_bounds__(256) void pad_kernel(const float* __restrict__ cen, float* __restrict__ cenpad){
  int idx = blockIdx.x*256 + threadIdx.x;  // exactly 6,422,528 threads
  int px = idx % 112; int t = idx / 112; int py = t % 112; int bc = t / 112;
  int y = py - 8, x = px - 8;
  float v = 0.f;
  if (y >= 0 && y < 96 && x >= 0 && x < 96) v = cen[(size_t)bc*9216 + y*96 + x];
  cenpad[idx] = v;
}

// ---- prep: build conv weights in bf16, fragment-ready layout
// Wb[((i*18 + kc)*256 + o)*32 + k'] where k = t*64 + c, kc=k>>5, k'=k&31
__global__ __launch_bounds__(256) void prep_kernel(const float* __restrict__ sumw,
    const float* __restrict__ kw, const float* __restrict__ vw, unsigned short* __restrict__ Wb){
  int idx = blockIdx.x*256 + threadIdx.x;  // exactly 589,824
  int o = idx & 255; int r = idx >> 8; int c = r & 63; r >>= 6; int t = r % 9; int i = r / 9;
  float l0 = sumw[(i*64 + c)*2 + 0], l1 = sumw[(i*64 + c)*2 + 1];
  float m = fmaxf(l0, l1);
  float e0 = expf(l0 - m), e1 = expf(l1 - m);
  float inv = 1.f/(e0 + e1);
  float sw0 = e0*inv, sw1 = e1*inv;
  const float* wsrc = (o < 128) ? (kw + ((size_t)i*128 + o)*512 + c)
                                : (vw + ((size_t)i*128 + (o-128))*512 + c);
  float A = 0.f;
  #pragma unroll
  for (int j = 0; j < 8; ++j) A += wsrc[j*64];
  float val;
  if (t == 4) {
    val = A;  // center tap: all mixed kernels have weight 1 at center (sw0+sw1=1)
  } else {
    const int tmap[9] = {0,1,2,7,0,3,6,5,4};
    int j = tmap[t];
    val = -(wsrc[j*64]*sw0 + A*sw1*0.125f);
  }
  int k = t*64 + c;
  Wb[(((size_t)i*18 + (k>>5))*256 + o)*32 + (k&31)] = f2bf(val);
}

// ---- Q projection: qbuf[i][b][oq][s] f32 = q_w[i] @ cen
__global__ __launch_bounds__(256) void qproj_kernel(const float* __restrict__ cen,
    const float* __restrict__ qw, float* __restrict__ qbuf){
  __shared__ float WT[64][16];  // [c][oq]
  int tid = threadIdx.x;
  int st = blockIdx.x; int ib = blockIdx.y; int i = ib >> 3, b = ib & 7;
  #pragma unroll
  for (int e = 0; e < 4; ++e) {
    int f = e*256 + tid; int c = f >> 4, o = f & 15;
    WT[c][o] = qw[(size_t)i*1024 + o*64 + c];
  }
  __syncthreads();
  int s = st*256 + tid;
  float acc[16];
  #pragma unroll
  for (int o = 0; o < 16; ++o) acc[o] = 0.f;
  const float* cb = cen + (size_t)b*64*9216 + s;
  for (int c = 0; c < 64; ++c) {
    float xv = cb[(size_t)c*9216];
    #pragma unroll
    for (int o4 = 0; o4 < 4; ++o4) {
      float4 w = *(const float4*)&WT[c][o4*4];
      acc[o4*4+0] = fmaf(w.x, xv, acc[o4*4+0]);
      acc[o4*4+1] = fmaf(w.y, xv, acc[o4*4+1]);
      acc[o4*4+2] = fmaf(w.z, xv, acc[o4*4+2]);
      acc[o4*4+3] = fmaf(w.w, xv, acc[o4*4+3]);
    }
  }
  float* qb = qbuf + ((size_t)(i*8 + b)*16)*9216 + s;
  #pragma unroll
  for (int o = 0; o < 16; ++o) qb[(size_t)o*9216] = acc[o];
}

// ---- conv K/V via MFMA: per (i,b) GEMM [256 o] x [576 k] x [9216 s] -> bf16 KV
// block 256 thr = 4 waves (2 wm x 2 wn); tile O=256 x S=128; K chunks of 32
// A (W): direct global short8 loads from frag-ready Wb (L2-resident)
// B (X): f32 gather of shifted cen -> cvt bf16 -> LDS [128 s][36 k] (72B rows)
__global__ __launch_bounds__(256) void conv_kv_mfma(const float* __restrict__ cenpad,
    const unsigned short* __restrict__ Wb, unsigned short* __restrict__ KV){
  __shared__ char Xs[128*72];
  const int tid = threadIdx.x;
  const int st = blockIdx.x, ib = blockIdx.z;
  const int i = ib >> 3, b = ib & 7;
  const int dil = 1 << i;
  const int s0 = st*128;
  const int wave = tid >> 6, lane = tid & 63;
  const int wm = wave >> 1, wn = wave & 1;
  const int l15 = lane & 15, l4 = lane >> 4;
  // staging mapping: thread covers (s_idx, k' = khalf*16 .. +15)
  const int s_idx = tid & 127;
  const int khalf = tid >> 7;
  const int s = s0 + s_idx;
  const int y = s / 96, x = s - y*96;
  const float* cb = cenpad + (size_t)b*802816 + (size_t)(y+8)*112 + (x+8);

  f32x4 acc[8][4];
  #pragma unroll
  for (int mf = 0; mf < 8; ++mf)
    #pragma unroll
    for (int nf = 0; nf < 4; ++nf)
      acc[mf][nf] = (f32x4){0.f, 0.f, 0.f, 0.f};

  const unsigned short* Wi = Wb + (size_t)i*18*8192;

  for (int kc = 0; kc < 18; ++kc) {
    // ---- A fragments: lane (l15 -> o row, l4 -> k-slot), 16B coalesced
    short8 a[8];
    const unsigned short* ap = Wi + (size_t)kc*8192 + (size_t)(wm*128 + l15)*32 + l4*8;
    #pragma unroll
    for (int mf = 0; mf < 8; ++mf) a[mf] = *(const short8*)(ap + mf*512);
    // ---- X gather (f32, always 4B-aligned regardless of dilation shift)
    const int t = kc >> 1;
    const int cbase = (kc & 1)*32 + khalf*16;
    const int dy = (t/3 - 1)*dil, dx = (t - (t/3)*3 - 1)*dil;
    const float* p = cb + (size_t)cbase*12544 + dy*112 + dx;
    float v[16];
    #pragma unroll
    for (int j = 0; j < 16; ++j) v[j] = p[(size_t)j*12544];
    __syncthreads();   // prev iteration's B-frag reads done
    unsigned int pk[8];
    #pragma unroll
    for (int j = 0; j < 8; ++j)
      pk[j] = (unsigned int)fbits(v[2*j]) | ((unsigned int)fbits(v[2*j+1]) << 16);
    char* wp = Xs + s_idx*72 + khalf*32;
    #pragma unroll
    for (int w = 0; w < 4; ++w) *(uint2*)(wp + w*8) = make_uint2(pk[2*w], pk[2*w+1]);
    __syncthreads();
    // ---- B fragments from LDS (b64 pairs, 72B rows -> conflict-free)
    short8 bfr[4];
    #pragma unroll
    for (int nf = 0; nf < 4; ++nf) {
      const char* rp = Xs + (wn*64 + nf*16 + l15)*72 + l4*16;
      uint2 lo = *(const uint2*)rp;
      uint2 hi = *(const uint2*)(rp + 8);
      uint4 tb = make_uint4(lo.x, lo.y, hi.x, hi.y);
      bfr[nf] = *(short8*)&tb;
    }
    // ---- MFMA
    #pragma unroll
    for (int mf = 0; mf < 8; ++mf)
      #pragma unroll
      for (int nf = 0; nf < 4; ++nf)
        acc[mf][nf] = __builtin_amdgcn_mfma_f32_16x16x32_bf16(a[mf], bfr[nf], acc[mf][nf], 0, 0, 0);
  }

  // ---- epilogue: C/D mapping row=(l>>4)*4+r, col=l&15
  #pragma unroll
  for (int mf = 0; mf < 8; ++mf) {
    #pragma unroll
    for (int nf = 0; nf < 4; ++nf) {
      int scol = s0 + wn*64 + nf*16 + l15;
      int obase = wm*128 + mf*16 + l4*4;
      #pragma unroll
      for (int r = 0; r < 4; ++r)
        KV[((size_t)ib*256 + obase + r)*9216 + scol] = fbits(acc[mf][nf][r]);
    }
  }
}

// ---- scores: per (b,hh,chunk of 1024 s): partial 16x128 dots + row sumsq
__global__ __launch_bounds__(256) void scores_kernel(const unsigned short* __restrict__ KV,
    const float* __restrict__ qbuf, float* __restrict__ spart,
    float* __restrict__ kkpart, float* __restrict__ qqpart){
  __shared__ float Klds[64][128];  // [s][kr]
  __shared__ float Qlds[16][64];   // [qr][s]
  const int tid = threadIdx.x;
  const int chunk = blockIdx.x, hh = blockIdx.y, b = blockIdx.z;
  const int kr = tid & 127, qrg = (tid >> 7) * 8;
  float acc[8] = {0,0,0,0,0,0,0,0};
  float kacc = 0.f, qacc = 0.f;
  const int skr = tid >> 2;
  const int sq16 = (tid & 3) * 16;
  const int qrow = tid >> 4, qoff = (tid & 15) * 4;
  const float* qsrc = qbuf + ((size_t)(((qrow & 3)*8 + b)*16 + hh*4 + (qrow >> 2)))*9216;

  for (int sc = 0; sc < 16; ++sc) {
    int sb = chunk*1024 + sc*64;
    #pragma unroll
    for (int p = 0; p < 2; ++p) {
      int krr = p*64 + skr;
      int ii = krr & 3, oo = hh*32 + (krr >> 2);
      const unsigned short* src = KV + ((size_t)((ii*8 + b)*256 + oo))*9216 + sb + sq16;
      uint4 u0 = *(const uint4*)src;
      uint4 u1 = *(const uint4*)(src + 8);
      Klds[sq16+ 0][krr] = bflo(u0.x); Klds[sq16+ 1][krr] = bfhi(u0.x);
      Klds[sq16+ 2][krr] = bflo(u0.y); Klds[sq16+ 3][krr] = bfhi(u0.y);
      Klds[sq16+ 4][krr] = bflo(u0.z); Klds[sq16+ 5][krr] = bfhi(u0.z);
      Klds[sq16+ 6][krr] = bflo(u0.w); Klds[sq16+ 7][krr] = bfhi(u0.w);
      Klds[sq16+ 8][krr] = bflo(u1.x); Klds[sq16+ 9][krr] = bfhi(u1.x);
      Klds[sq16+10][krr] = bflo(u1.y); Klds[sq16+11][krr] = bfhi(u1.y);
      Klds[sq16+12][krr] = bflo(u1.z); Klds[sq16+13][krr] = bfhi(u1.z);
      Klds[sq16+14][krr] = bflo(u1.w); Klds[sq16+15][krr] = bfhi(u1.w);
    }
    *(float4*)&Qlds[qrow][qoff] = *(const float4*)(qsrc + sb + qoff);
    __syncthreads();
    #pragma unroll 4
    for (int s4 = 0; s4 < 16; ++s4) {
      float k0 = Klds[s4*4+0][kr], k1 = Klds[s4*4+1][kr];
      float k2 = Klds[s4*4+2][kr], k3 = Klds[s4*4+3][kr];
      if (tid < 128) kacc += k0*k0 + k1*k1 + k2*k2 + k3*k3;
      #pragma unroll
      for (int q = 0; q < 8; ++q) {
        float4 qv = *(const float4*)&Qlds[qrg + q][s4*4];
        acc[q] += k0*qv.x + k1*qv.y + k2*qv.z + k3*qv.w;
      }
      if (tid >= 128 && tid < 144) {
        float4 qv = *(const float4*)&Qlds[tid & 15][s4*4];
        qacc += qv.x*qv.x + qv.y*qv.y + qv.z*qv.z + qv.w*qv.w;
      }
    }
    __syncthreads();
  }
  int pb = (b*4 + hh)*9 + chunk;
  #pragma unroll
  for (int q = 0; q < 8; ++q) spart[(size_t)pb*2048 + (qrg+q)*128 + kr] = acc[q];
  if (tid < 128) kkpart[(size_t)pb*128 + tid] = kacc;
  if (tid >= 128 && tid < 144) qqpart[(size_t)pb*16 + (tid - 128)] = qacc;
}

// ---- softmax: reduce partials, l2-normalize scale, instance-norm, row softmax -> attnT[kr][qr]
__global__ __launch_bounds__(256) void softmax_kernel(const float* __restrict__ spart,
    const float* __restrict__ kkpart, const float* __restrict__ qqpart, float* __restrict__ attnT){
  const int pb = blockIdx.x, tid = threadIdx.x;
  const int qr = tid >> 4, g = tid & 15;
  __shared__ float kkl[128];
  __shared__ float qql[16];
  __shared__ float red[8];
  __shared__ float stats[2];
  float sv[8] = {0,0,0,0,0,0,0,0};
  for (int ch = 0; ch < 9; ++ch) {
    const float* p = spart + ((size_t)(pb*9 + ch))*2048 + qr*128 + g*8;
    #pragma unroll
    for (int e = 0; e < 8; ++e) sv[e] += p[e];
  }
  if (tid < 128) { float ssum = 0.f; for (int ch = 0; ch < 9; ++ch) ssum += kkpart[(size_t)(pb*9+ch)*128 + tid]; kkl[tid] = ssum; }
  if (tid < 16)  { float ssum = 0.f; for (int ch = 0; ch < 9; ++ch) ssum += qqpart[(size_t)(pb*9+ch)*16 + tid]; qql[tid] = ssum; }
  __syncthreads();
  float qn = fmaxf(sqrtf(qql[qr]), 1e-12f);
  float lsum = 0.f, lsq = 0.f;
  #pragma unroll
  for (int e = 0; e < 8; ++e) {
    float kn = fmaxf(sqrtf(kkl[g*8+e]), 1e-12f);
    float v = sv[e] / (qn * kn * 96.0f);
    sv[e] = v; lsum += v; lsq += v*v;
  }
  #pragma unroll
  for (int m = 1; m <= 32; m <<= 1) { lsum += __shfl_xor(lsum, m); lsq += __shfl_xor(lsq, m); }
  if ((tid & 63) == 0) { red[tid >> 6] = lsum; red[4 + (tid >> 6)] = lsq; }
  __syncthreads();
  if (tid == 0) {
    float ts = red[0]+red[1]+red[2]+red[3];
    float tq = red[4]+red[5]+red[6]+red[7];
    float mean = ts / 2048.0f;
    float var = tq / 2048.0f - mean*mean;
    stats[0] = mean; stats[1] = rsqrtf(var + 1e-5f);
  }
  __syncthreads();
  float mean = stats[0], inv = stats[1];
  float mx = -1e30f;
  #pragma unroll
  for (int e = 0; e < 8; ++e) { sv[e] = (sv[e] - mean) * inv; mx = fmaxf(mx, sv[e]); }
  #pragma unroll
  for (int m = 1; m <= 8; m <<= 1) mx = fmaxf(mx, __shfl_xor(mx, m));
  float es = 0.f;
  #pragma unroll
  for (int e = 0; e < 8; ++e) { sv[e] = expf(sv[e] - mx); es += sv[e]; }
  #pragma unroll
  for (int m = 1; m <= 8; m <<= 1) es += __shfl_xor(es, m);
  float rinv = 1.0f / es;
  #pragma unroll
  for (int e = 0; e < 8; ++e) attnT[(size_t)pb*2048 + (g*8+e)*16 + qr] = sv[e] * rinv;
}

// ---- PV: out[b][hh*16+qr][s] = sum_kr attn * V
__global__ __launch_bounds__(256) void pv_kernel(const unsigned short* __restrict__ KV,
    const float* __restrict__ attnT, float* __restrict__ outbuf){
  __shared__ float at[128][16];
  int tid = threadIdx.x;
  int st = blockIdx.x, hh = blockIdx.y, b = blockIdx.z;
  const float* ap = attnT + ((size_t)(b*4 + hh))*2048;
  #pragma unroll
  for (int e = 0; e < 8; ++e) ((float*)at)[e*256 + tid] = ap[e*256 + tid];
  __syncthreads();
  int sbase = st*1024 + tid*4;
  float acc[16][4];
  #pragma unroll
  for (int q = 0; q < 16; ++q)
    #pragma unroll
    for (int p = 0; p < 4; ++p) acc[q][p] = 0.f;
  #pragma unroll 2
  for (int kr = 0; kr < 128; ++kr) {
    int ii = kr & 3, oo = 128 + hh*32 + (kr >> 2);
    const unsigned short* vp = KV + ((size_t)((ii*8 + b)*256 + oo))*9216 + sbase;
    uint2 u = *(const uint2*)vp;
    float v0 = bflo(u.x), v1 = bfhi(u.x), v2 = bflo(u.y), v3 = bfhi(u.y);
    #pragma unroll
    for (int q4 = 0; q4 < 4; ++q4) {
      float4 a = *(const float4*)&at[kr][q4*4];
      float av[4] = {a.x, a.y, a.z, a.w};
      #pragma unroll
      for (int j = 0; j < 4; ++j) {
        acc[q4*4+j][0] = fmaf(av[j], v0, acc[q4*4+j][0]);
        acc[q4*4+j][1] = fmaf(av[j], v1, acc[q4*4+j][1]);
        acc[q4*4+j][2] = fmaf(av[j], v2, acc[q4*4+j][2]);
        acc[q4*4+j][3] = fmaf(av[j], v3, acc[q4*4+j][3]);
      }
    }
  }
  float* ob = outbuf + ((size_t)(b*64 + hh*16))*9216 + sbase;
  #pragma unroll
  for (int q = 0; q < 16; ++q) {
    float4 w = make_float4(acc[q][0], acc[q][1], acc[q][2], acc[q][3]);
    *(float4*)(ob + (size_t)q*9216) = w;
  }
}

// ---- 1x1 out conv -> d_out (pre-BN)
__global__ __launch_bounds__(256) void outconv_kernel(const float* __restrict__ outbuf,
    const float* __restrict__ ow, float* __restrict__ dout){
  __shared__ float WT[64][64];  // [c][o]
  int tid = threadIdx.x; int st = blockIdx.x; int b = blockIdx.y;
  #pragma unroll
  for (int e = 0; e < 16; ++e) {
    int f = e*256 + tid; int c = f >> 6, o = f & 63;
    WT[c][o] = ow[o*64 + c];
  }
  __syncthreads();
  int s = st*256 + tid;
  float acc[64];
  #pragma unroll
  for (int o = 0; o < 64; ++o) acc[o] = 0.f;
  for (int c = 0; c < 64; ++c) {
    float xv = outbuf[((size_t)(b*64 + c))*9216 + s];
    #pragma unroll
    for (int o4 = 0; o4 < 16; ++o4) {
      float4 w = *(const float4*)&WT[c][o4*4];
      acc[o4*4+0] = fmaf(w.x, xv, acc[o4*4+0]);
      acc[o4*4+1] = fmaf(w.y, xv, acc[o4*4+1]);
      acc[o4*4+2] = fmaf(w.z, xv, acc[o4*4+2]);
      acc[o4*4+3] = fmaf(w.w, xv, acc[o4*4+3]);
    }
  }
  #pragma unroll
  for (int o = 0; o < 64; ++o) dout[((size_t)(b*64 + o))*9216 + s] = acc[o];
}

// ---- BN stats per channel over (b, h, w)
__global__ __launch_bounds__(256) void bnstats_kernel(const float* __restrict__ yb, float* __restrict__ bn){
  int o = blockIdx.x; int tid = threadIdx.x;
  float s = 0.f, sq = 0.f;
  for (int idx = tid; idx < 73728; idx += 256) {
    int b = idx / 9216, sp = idx - b*9216;
    float v = yb[((size_t)(b*64 + o))*9216 + sp];
    s += v; sq += v*v;
  }
  #pragma unroll
  for (int m = 1; m <= 32; m <<= 1) { s += __shfl_xor(s, m); sq += __shfl_xor(sq, m); }
  __shared__ float r0[4], r1[4];
  if ((tid & 63) == 0) { r0[tid >> 6] = s; r1[tid >> 6] = sq; }
  __syncthreads();
  if (tid == 0) {
    float ts = r0[0]+r0[1]+r0[2]+r0[3];
    float tq = r1[0]+r1[1]+r1[2]+r1[3];
    float mean = ts / 73728.f;
    float var = tq / 73728.f - mean*mean;
    bn[o] = mean;
    bn[64 + o] = rsqrtf(var + 1e-5f);
  }
}

// ---- BN apply + ReLU (in place on d_out), float4
__global__ __launch_bounds__(256) void bnapply_kernel(float* __restrict__ yb,
    const float* __restrict__ bn, const float* __restrict__ gamma, const float* __restrict__ beta){
  int gid = blockIdx.x*256 + threadIdx.x;  // exactly 1,179,648 float4s
  int o = (gid / 2304) & 63;
  float mean = bn[o], inv = bn[64 + o];
  float g = gamma[o], be = beta[o];
  float4 v = ((const float4*)yb)[gid];
  v.x = fmaxf((v.x - mean)*inv*g + be, 0.f);
  v.y = fmaxf((v.y - mean)*inv*g + be, 0.f);
  v.z = fmaxf((v.z - mean)*inv*g + be, 0.f);
  v.w = fmaxf((v.w - mean)*inv*g + be, 0.f);
  ((float4*)yb)[gid] = v;
}

extern "C" void kernel_launch(void* const* d_in, const int* in_sizes, int n_in,
                              void* d_out, int out_size, void* d_ws, size_t ws_size,
                              hipStream_t stream) {
  const float* cen   = (const float*)d_in[0];
  const float* sumw  = (const float*)d_in[1];
  const float* qw    = (const float*)d_in[2];
  const float* kw    = (const float*)d_in[3];
  const float* vw    = (const float*)d_in[4];
  const float* ow    = (const float*)d_in[5];
  const float* gamma = (const float*)d_in[6];
  const float* beta  = (const float*)d_in[7];

  char* ws = (char*)d_ws;
  float*          cenpad = (float*)(ws + WS_CENPAD);
  unsigned short* Wb     = (unsigned short*)(ws + WS_W);
  float*          qbuf   = (float*)(ws + WS_Q);
  unsigned short* KV     = (unsigned short*)(ws + WS_KV);
  float*          spart  = (float*)(ws + WS_SPART);
  float*          kkp    = (float*)(ws + WS_KKP);
  float*          qqp    = (float*)(ws + WS_QQP);
  float*          attnT  = (float*)(ws + WS_ATTN);
  float*          outbuf = (float*)(ws + WS_OUT);
  float*          bn     = (float*)(ws + WS_BN);

  pad_kernel    <<<25088, 256, 0, stream>>>(cen, cenpad);
  prep_kernel   <<<2304, 256, 0, stream>>>(sumw, kw, vw, Wb);
  qproj_kernel  <<<dim3(36, 32), 256, 0, stream>>>(cen, qw, qbuf);
  conv_kv_mfma  <<<dim3(72, 1, 32), 256, 0, stream>>>(cenpad, Wb, KV);
  scores_kernel <<<dim3(9, 4, 8), 256, 0, stream>>>(KV, qbuf, spart, kkp, qqp);
  softmax_kernel<<<32, 256, 0, stream>>>(spart, kkp, qqp, attnT);
  pv_kernel     <<<dim3(9, 4, 8), 256, 0, stream>>>(KV, attnT, outbuf);
  outconv_kernel<<<dim3(36, 8), 256, 0, stream>>>(outbuf, ow, (float*)d_out);
  bnstats_kernel<<<64, 256, 0, stream>>>((const float*)d_out, bn);
  bnapply_kernel<<<4608, 256, 0, stream>>>((float*)d_out, bn, gamma, beta);
}

// Round 3
// 551.225 us; speedup vs baseline: 2.8305x; 1.1598x over previous
//
#include <hip/hip_runtime.h>
#include <hip/hip_bf16.h>

// ---------------- sizes ----------------
// B=8, C=64, H=W=96, S=9216, NH=4 (dil=1,2,4,8), NL=8, hid=16
// KV rows per (i,b): 256 (0..127 = K via k_w, 128..255 = V via v_w)
// conv GEMM per (i,b): [256 o] x [576 k = tap*64+c] x [9216 s], bf16 MFMA

// ---------------- workspace layout (bytes) ----------------
#define WS_CENPAD 0UL           // bf16 [8][64][112][112]     = 12,845,056
#define WS_W      25690112UL    // bf16 [4][18][256][32]      =  1,179,648 (frag-ready)
#define WS_Q      28049408UL    // f32 [4][8][16][9216]       = 18,874,368
#define WS_KV     46923776UL    // bf16 [4][8][256][9216]     = 150,994,944
#define WS_SPART  197918720UL   // f32 [288][2048]            =  2,359,296
#define WS_KKP    200278016UL   // f32 [288][128]             =    147,456
#define WS_QQP    200425472UL   // f32 [288][16]              =     18,432
#define WS_ATTN   200443904UL   // f32 [32][128][16]          =    262,144
#define WS_OUT    200706048UL   // f32 [8][64][9216]          = 18,874,368
#define WS_BN     219580416UL   // f32 [128]

typedef __attribute__((ext_vector_type(8))) short short8;
typedef __attribute__((ext_vector_type(4))) float f32x4;

__device__ __forceinline__ float bflo(unsigned int u){ return __uint_as_float(u<<16); }
__device__ __forceinline__ float bfhi(unsigned int u){ return __uint_as_float(u & 0xffff0000u); }
__device__ __forceinline__ unsigned short f2bf(float f){
  unsigned int u = __float_as_uint(f);
  return (unsigned short)((u + 0x7fffu + ((u>>16)&1u)) >> 16);
}
__device__ __forceinline__ unsigned short fbits(float f){
  __hip_bfloat16 h = __float2bfloat16(f);
  return __builtin_bit_cast(unsigned short, h);
}

// ---- pad: cen [8,64,96,96] f32 -> cenbf [8,64,112,112] bf16 (8-halo zeros)
__global__ __launch_bounds__(256) void pad_kernel(const float* __restrict__ cen, unsigned short* __restrict__ cenbf){
  int idx = blockIdx.x*256 + threadIdx.x;  // exactly 6,422,528 threads
  int px = idx % 112; int t = idx / 112; int py = t % 112; int bc = t / 112;
  int y = py - 8, x = px - 8;
  float v = 0.f;
  if (y >= 0 && y < 96 && x >= 0 && x < 96) v = cen[(size_t)bc*9216 + y*96 + x];
  cenbf[idx] = fbits(v);
}

// ---- prep: build conv weights in bf16, fragment-ready layout
// Wb[((i*18 + kc)*256 + o)*32 + k'] where k = t*64 + c, kc=k>>5, k'=k&31
__global__ __launch_bounds__(256) void prep_kernel(const float* __restrict__ sumw,
    const float* __restrict__ kw, const float* __restrict__ vw, unsigned short* __restrict__ Wb){
  int idx = blockIdx.x*256 + threadIdx.x;  // exactly 589,824
  int o = idx & 255; int r = idx >> 8; int c = r & 63; r >>= 6; int t = r % 9; int i = r / 9;
  float l0 = sumw[(i*64 + c)*2 + 0], l1 = sumw[(i*64 + c)*2 + 1];
  float m = fmaxf(l0, l1);
  float e0 = expf(l0 - m), e1 = expf(l1 - m);
  float inv = 1.f/(e0 + e1);
  float sw0 = e0*inv, sw1 = e1*inv;
  const float* wsrc = (o < 128) ? (kw + ((size_t)i*128 + o)*512 + c)
                                : (vw + ((size_t)i*128 + (o-128))*512 + c);
  float A = 0.f;
  #pragma unroll
  for (int j = 0; j < 8; ++j) A += wsrc[j*64];
  float val;
  if (t == 4) {
    val = A;  // center tap: all mixed kernels have weight 1 at center (sw0+sw1=1)
  } else {
    const int tmap[9] = {0,1,2,7,0,3,6,5,4};
    int j = tmap[t];
    val = -(wsrc[j*64]*sw0 + A*sw1*0.125f);
  }
  int k = t*64 + c;
  Wb[(((size_t)i*18 + (k>>5))*256 + o)*32 + (k&31)] = f2bf(val);
}

// ---- Q projection: qbuf[i][b][oq][s] f32 = q_w[i] @ cen
__global__ __launch_bounds__(256) void qproj_kernel(const float* __restrict__ cen,
    const float* __restrict__ qw, float* __restrict__ qbuf){
  __shared__ float WT[64][16];  // [c][oq]
  int tid = threadIdx.x;
  int st = blockIdx.x; int ib = blockIdx.y; int i = ib >> 3, b = ib & 7;
  #pragma unroll
  for (int e = 0; e < 4; ++e) {
    int f = e*256 + tid; int c = f >> 4, o = f & 15;
    WT[c][o] = qw[(size_t)i*1024 + o*64 + c];
  }
  __syncthreads();
  int s = st*256 + tid;
  float acc[16];
  #pragma unroll
  for (int o = 0; o < 16; ++o) acc[o] = 0.f;
  const float* cb = cen + (size_t)b*64*9216 + s;
  for (int c = 0; c < 64; ++c) {
    float xv = cb[(size_t)c*9216];
    #pragma unroll
    for (int o4 = 0; o4 < 4; ++o4) {
      float4 w = *(const float4*)&WT[c][o4*4];
      acc[o4*4+0] = fmaf(w.x, xv, acc[o4*4+0]);
      acc[o4*4+1] = fmaf(w.y, xv, acc[o4*4+1]);
      acc[o4*4+2] = fmaf(w.z, xv, acc[o4*4+2]);
      acc[o4*4+3] = fmaf(w.w, xv, acc[o4*4+3]);
    }
  }
  float* qb = qbuf + ((size_t)(i*8 + b)*16)*9216 + s;
  #pragma unroll
  for (int o = 0; o < 16; ++o) qb[(size_t)o*9216] = acc[o];
}

// ---- conv K/V via MFMA: per (i,b) GEMM [256 o] x [576 k] x [9216 s] -> bf16 KV
// 512 thr = 8 waves (2 wm x 4 wn); tile O=256 x S=256; K chunks of 32
// Pipelined: 1 barrier/chunk, double-buffered LDS, reg-prefetch of X gather.
// A (W): direct global short8 loads from frag-ready Wb (L2-resident)
// B (X): bf16 gather of shifted cen -> pack -> LDS [2][256 s][72 B]
__global__ __launch_bounds__(512, 2) void conv_kv_mfma(const unsigned short* __restrict__ cenbf,
    const unsigned short* __restrict__ Wb, unsigned short* __restrict__ KV){
  __shared__ char Xs[2][256*72];
  const int tid = threadIdx.x;
  const int st = blockIdx.x, ib = blockIdx.z;
  const int i = ib >> 3, b = ib & 7;
  const int dil = 1 << i;
  const int s0 = st*256;
  const int wave = tid >> 6, lane = tid & 63;
  const int wm = wave >> 2, wn = wave & 3;
  const int l15 = lane & 15, l4 = lane >> 4;
  // staging mapping: thread covers (s_idx, k' = khalf*16 .. +15)
  const int s_idx = tid & 255;
  const int khalf = tid >> 8;
  const int s = s0 + s_idx;
  const int y = s / 96, x = s - y*96;
  const unsigned short* cb = cenbf + (size_t)b*802816 + (size_t)(y+8)*112 + (x+8);

  f32x4 acc[8][4];
  #pragma unroll
  for (int mf = 0; mf < 8; ++mf)
    #pragma unroll
    for (int nf = 0; nf < 4; ++nf)
      acc[mf][nf] = (f32x4){0.f, 0.f, 0.f, 0.f};

  const unsigned short* Wi = Wb + (size_t)i*18*8192;

  unsigned short vs[16];
  auto gather = [&](int kn){
    int t = kn >> 1;
    int cbase = (kn & 1)*32 + khalf*16;
    int dy = (t/3 - 1)*dil, dx = (t - (t/3)*3 - 1)*dil;
    const unsigned short* p = cb + (size_t)cbase*12544 + (dy*112 + dx);
    #pragma unroll
    for (int j = 0; j < 16; ++j) vs[j] = p[(size_t)j*12544];
  };

  gather(0);   // prologue
  int buf = 0;
  for (int kc = 0; kc < 18; ++kc) {
    // ---- pack prev gather & write LDS buf
    char* wp = Xs[buf] + s_idx*72 + khalf*32;
    #pragma unroll
    for (int w = 0; w < 4; ++w) {
      unsigned int p0 = (unsigned int)vs[4*w+0] | ((unsigned int)vs[4*w+1] << 16);
      unsigned int p1 = (unsigned int)vs[4*w+2] | ((unsigned int)vs[4*w+3] << 16);
      *(uint2*)(wp + w*8) = make_uint2(p0, p1);
    }
    // ---- prefetch next chunk's gather (hidden under this chunk's MFMA)
    gather(kc < 17 ? kc + 1 : 17);
    // ---- A fragments for this chunk: lane (l15 -> o row, l4 -> k-slot), 16B coalesced
    short8 a[8];
    const unsigned short* ap = Wi + (size_t)kc*8192 + (size_t)(wm*128 + l15)*32 + l4*8;
    #pragma unroll
    for (int mf = 0; mf < 8; ++mf) a[mf] = *(const short8*)(ap + mf*512);
    __syncthreads();
    // ---- B fragments from LDS (72B rows -> conflict-free)
    short8 bfr[4];
    #pragma unroll
    for (int nf = 0; nf < 4; ++nf) {
      const char* rp = Xs[buf] + (wn*64 + nf*16 + l15)*72 + l4*16;
      uint2 lo = *(const uint2*)rp;
      uint2 hi = *(const uint2*)(rp + 8);
      uint4 tb = make_uint4(lo.x, lo.y, hi.x, hi.y);
      bfr[nf] = *(short8*)&tb;
    }
    // ---- MFMA
    #pragma unroll
    for (int mf = 0; mf < 8; ++mf)
      #pragma unroll
      for (int nf = 0; nf < 4; ++nf)
        acc[mf][nf] = __builtin_amdgcn_mfma_f32_16x16x32_bf16(a[mf], bfr[nf], acc[mf][nf], 0, 0, 0);
    buf ^= 1;
  }

  // ---- epilogue: C/D mapping row=(l>>4)*4+r, col=l&15
  #pragma unroll
  for (int mf = 0; mf < 8; ++mf) {
    #pragma unroll
    for (int nf = 0; nf < 4; ++nf) {
      int scol = s0 + wn*64 + nf*16 + l15;
      int obase = wm*128 + mf*16 + l4*4;
      #pragma unroll
      for (int r = 0; r < 4; ++r)
        KV[((size_t)ib*256 + obase + r)*9216 + scol] = fbits(acc[mf][nf][r]);
    }
  }
}

// ---- scores: per (b,hh,chunk of 1024 s): partial 16x128 dots + row sumsq
__global__ __launch_bounds__(256) void scores_kernel(const unsigned short* __restrict__ KV,
    const float* __restrict__ qbuf, float* __restrict__ spart,
    float* __restrict__ kkpart, float* __restrict__ qqpart){
  __shared__ float Klds[64][128];  // [s][kr]
  __shared__ float Qlds[16][64];   // [qr][s]
  const int tid = threadIdx.x;
  const int chunk = blockIdx.x, hh = blockIdx.y, b = blockIdx.z;
  const int kr = tid & 127, qrg = (tid >> 7) * 8;
  float acc[8] = {0,0,0,0,0,0,0,0};
  float kacc = 0.f, qacc = 0.f;
  const int skr = tid >> 2;
  const int sq16 = (tid & 3) * 16;
  const int qrow = tid >> 4, qoff = (tid & 15) * 4;
  const float* qsrc = qbuf + ((size_t)(((qrow & 3)*8 + b)*16 + hh*4 + (qrow >> 2)))*9216;

  for (int sc = 0; sc < 16; ++sc) {
    int sb = chunk*1024 + sc*64;
    #pragma unroll
    for (int p = 0; p < 2; ++p) {
      int krr = p*64 + skr;
      int ii = krr & 3, oo = hh*32 + (krr >> 2);
      const unsigned short* src = KV + ((size_t)((ii*8 + b)*256 + oo))*9216 + sb + sq16;
      uint4 u0 = *(const uint4*)src;
      uint4 u1 = *(const uint4*)(src + 8);
      Klds[sq16+ 0][krr] = bflo(u0.x); Klds[sq16+ 1][krr] = bfhi(u0.x);
      Klds[sq16+ 2][krr] = bflo(u0.y); Klds[sq16+ 3][krr] = bfhi(u0.y);
      Klds[sq16+ 4][krr] = bflo(u0.z); Klds[sq16+ 5][krr] = bfhi(u0.z);
      Klds[sq16+ 6][krr] = bflo(u0.w); Klds[sq16+ 7][krr] = bfhi(u0.w);
      Klds[sq16+ 8][krr] = bflo(u1.x); Klds[sq16+ 9][krr] = bfhi(u1.x);
      Klds[sq16+10][krr] = bflo(u1.y); Klds[sq16+11][krr] = bfhi(u1.y);
      Klds[sq16+12][krr] = bflo(u1.z); Klds[sq16+13][krr] = bfhi(u1.z);
      Klds[sq16+14][krr] = bflo(u1.w); Klds[sq16+15][krr] = bfhi(u1.w);
    }
    *(float4*)&Qlds[qrow][qoff] = *(const float4*)(qsrc + sb + qoff);
    __syncthreads();
    #pragma unroll 4
    for (int s4 = 0; s4 < 16; ++s4) {
      float k0 = Klds[s4*4+0][kr], k1 = Klds[s4*4+1][kr];
      float k2 = Klds[s4*4+2][kr], k3 = Klds[s4*4+3][kr];
      if (tid < 128) kacc += k0*k0 + k1*k1 + k2*k2 + k3*k3;
      #pragma unroll
      for (int q = 0; q < 8; ++q) {
        float4 qv = *(const float4*)&Qlds[qrg + q][s4*4];
        acc[q] += k0*qv.x + k1*qv.y + k2*qv.z + k3*qv.w;
      }
      if (tid >= 128 && tid < 144) {
        float4 qv = *(const float4*)&Qlds[tid & 15][s4*4];
        qacc += qv.x*qv.x + qv.y*qv.y + qv.z*qv.z + qv.w*qv.w;
      }
    }
    __syncthreads();
  }
  int pb = (b*4 + hh)*9 + chunk;
  #pragma unroll
  for (int q = 0; q < 8; ++q) spart[(size_t)pb*2048 + (qrg+q)*128 + kr] = acc[q];
  if (tid < 128) kkpart[(size_t)pb*128 + tid] = kacc;
  if (tid >= 128 && tid < 144) qqpart[(size_t)pb*16 + (tid - 128)] = qacc;
}

// ---- softmax: reduce partials, l2-normalize scale, instance-norm, row softmax -> attnT[kr][qr]
__global__ __launch_bounds__(256) void softmax_kernel(const float* __restrict__ spart,
    const float* __restrict__ kkpart, const float* __restrict__ qqpart, float* __restrict__ attnT){
  const int pb = blockIdx.x, tid = threadIdx.x;
  const int qr = tid >> 4, g = tid & 15;
  __shared__ float kkl[128];
  __shared__ float qql[16];
  __shared__ float red[8];
  __shared__ float stats[2];
  float sv[8] = {0,0,0,0,0,0,0,0};
  for (int ch = 0; ch < 9; ++ch) {
    const float* p = spart + ((size_t)(pb*9 + ch))*2048 + qr*128 + g*8;
    #pragma unroll
    for (int e = 0; e < 8; ++e) sv[e] += p[e];
  }
  if (tid < 128) { float ssum = 0.f; for (int ch = 0; ch < 9; ++ch) ssum += kkpart[(size_t)(pb*9+ch)*128 + tid]; kkl[tid] = ssum; }
  if (tid < 16)  { float ssum = 0.f; for (int ch = 0; ch < 9; ++ch) ssum += qqpart[(size_t)(pb*9+ch)*16 + tid]; qql[tid] = ssum; }
  __syncthreads();
  float qn = fmaxf(sqrtf(qql[qr]), 1e-12f);
  float lsum = 0.f, lsq = 0.f;
  #pragma unroll
  for (int e = 0; e < 8; ++e) {
    float kn = fmaxf(sqrtf(kkl[g*8+e]), 1e-12f);
    float v = sv[e] / (qn * kn * 96.0f);
    sv[e] = v; lsum += v; lsq += v*v;
  }
  #pragma unroll
  for (int m = 1; m <= 32; m <<= 1) { lsum += __shfl_xor(lsum, m); lsq += __shfl_xor(lsq, m); }
  if ((tid & 63) == 0) { red[tid >> 6] = lsum; red[4 + (tid >> 6)] = lsq; }
  __syncthreads();
  if (tid == 0) {
    float ts = red[0]+red[1]+red[2]+red[3];
    float tq = red[4]+red[5]+red[6]+red[7];
    float mean = ts / 2048.0f;
    float var = tq / 2048.0f - mean*mean;
    stats[0] = mean; stats[1] = rsqrtf(var + 1e-5f);
  }
  __syncthreads();
  float mean = stats[0], inv = stats[1];
  float mx = -1e30f;
  #pragma unroll
  for (int e = 0; e < 8; ++e) { sv[e] = (sv[e] - mean) * inv; mx = fmaxf(mx, sv[e]); }
  #pragma unroll
  for (int m = 1; m <= 8; m <<= 1) mx = fmaxf(mx, __shfl_xor(mx, m));
  float es = 0.f;
  #pragma unroll
  for (int e = 0; e < 8; ++e) { sv[e] = expf(sv[e] - mx); es += sv[e]; }
  #pragma unroll
  for (int m = 1; m <= 8; m <<= 1) es += __shfl_xor(es, m);
  float rinv = 1.0f / es;
  #pragma unroll
  for (int e = 0; e < 8; ++e) attnT[(size_t)pb*2048 + (g*8+e)*16 + qr] = sv[e] * rinv;
}

// ---- PV: out[b][hh*16+qr][s] = sum_kr attn * V
__global__ __launch_bounds__(256) void pv_kernel(const unsigned short* __restrict__ KV,
    const float* __restrict__ attnT, float* __restrict__ outbuf){
  __shared__ float at[128][16];
  int tid = threadIdx.x;
  int st = blockIdx.x, hh = blockIdx.y, b = blockIdx.z;
  const float* ap = attnT + ((size_t)(b*4 + hh))*2048;
  #pragma unroll
  for (int e = 0; e < 8; ++e) ((float*)at)[e*256 + tid] = ap[e*256 + tid];
  __syncthreads();
  int sbase = st*1024 + tid*4;
  float acc[16][4];
  #pragma unroll
  for (int q = 0; q < 16; ++q)
    #pragma unroll
    for (int p = 0; p < 4; ++p) acc[q][p] = 0.f;
  #pragma unroll 2
  for (int kr = 0; kr < 128; ++kr) {
    int ii = kr & 3, oo = 128 + hh*32 + (kr >> 2);
    const unsigned short* vp = KV + ((size_t)((ii*8 + b)*256 + oo))*9216 + sbase;
    uint2 u = *(const uint2*)vp;
    float v0 = bflo(u.x), v1 = bfhi(u.x), v2 = bflo(u.y), v3 = bfhi(u.y);
    #pragma unroll
    for (int q4 = 0; q4 < 4; ++q4) {
      float4 a = *(const float4*)&at[kr][q4*4];
      float av[4] = {a.x, a.y, a.z, a.w};
      #pragma unroll
      for (int j = 0; j < 4; ++j) {
        acc[q4*4+j][0] = fmaf(av[j], v0, acc[q4*4+j][0]);
        acc[q4*4+j][1] = fmaf(av[j], v1, acc[q4*4+j][1]);
        acc[q4*4+j][2] = fmaf(av[j], v2, acc[q4*4+j][2]);
        acc[q4*4+j][3] = fmaf(av[j], v3, acc[q4*4+j][3]);
      }
    }
  }
  float* ob = outbuf + ((size_t)(b*64 + hh*16))*9216 + sbase;
  #pragma unroll
  for (int q = 0; q < 16; ++q) {
    float4 w = make_float4(acc[q][0], acc[q][1], acc[q][2], acc[q][3]);
    *(float4*)(ob + (size_t)q*9216) = w;
  }
}

// ---- 1x1 out conv -> d_out (pre-BN)
__global__ __launch_bounds__(256) void outconv_kernel(const float* __restrict__ outbuf,
    const float* __restrict__ ow, float* __restrict__ dout){
  __shared__ float WT[64][64];  // [c][o]
  int tid = threadIdx.x; int st = blockIdx.x; int b = blockIdx.y;
  #pragma unroll
  for (int e = 0; e < 16; ++e) {
    int f = e*256 + tid; int c = f >> 6, o = f & 63;
    WT[c][o] = ow[o*64 + c];
  }
  __syncthreads();
  int s = st*256 + tid;
  float acc[64];
  #pragma unroll
  for (int o = 0; o < 64; ++o) acc[o] = 0.f;
  for (int c = 0; c < 64; ++c) {
    float xv = outbuf[((size_t)(b*64 + c))*9216 + s];
    #pragma unroll
    for (int o4 = 0; o4 < 16; ++o4) {
      float4 w = *(const float4*)&WT[c][o4*4];
      acc[o4*4+0] = fmaf(w.x, xv, acc[o4*4+0]);
      acc[o4*4+1] = fmaf(w.y, xv, acc[o4*4+1]);
      acc[o4*4+2] = fmaf(w.z, xv, acc[o4*4+2]);
      acc[o4*4+3] = fmaf(w.w, xv, acc[o4*4+3]);
    }
  }
  #pragma unroll
  for (int o = 0; o < 64; ++o) dout[((size_t)(b*64 + o))*9216 + s] = acc[o];
}

// ---- BN stats per channel over (b, h, w)
__global__ __launch_bounds__(256) void bnstats_kernel(const float* __restrict__ yb, float* __restrict__ bn){
  int o = blockIdx.x; int tid = threadIdx.x;
  float s = 0.f, sq = 0.f;
  for (int idx = tid; idx < 73728; idx += 256) {
    int b = idx / 9216, sp = idx - b*9216;
    float v = yb[((size_t)(b*64 + o))*9216 + sp];
    s += v; sq += v*v;
  }
  #pragma unroll
  for (int m = 1; m <= 32; m <<= 1) { s += __shfl_xor(s, m); sq += __shfl_xor(sq, m); }
  __shared__ float r0[4], r1[4];
  if ((tid & 63) == 0) { r0[tid >> 6] = s; r1[tid >> 6] = sq; }
  __syncthreads();
  if (tid == 0) {
    float ts = r0[0]+r0[1]+r0[2]+r0[3];
    float tq = r1[0]+r1[1]+r1[2]+r1[3];
    float mean = ts / 73728.f;
    float var = tq / 73728.f - mean*mean;
    bn[o] = mean;
    bn[64 + o] = rsqrtf(var + 1e-5f);
  }
}

// ---- BN apply + ReLU (in place on d_out), float4
__global__ __launch_bounds__(256) void bnapply_kernel(float* __restrict__ yb,
    const float* __restrict__ bn, const float* __restrict__ gamma, const float* __restrict__ beta){
  int gid = blockIdx.x*256 + threadIdx.x;  // exactly 1,179,648 float4s
  int o = (gid / 2304) & 63;
  float mean = bn[o], inv = bn[64 + o];
  float g = gamma[o], be = beta[o];
  float4 v = ((const float4*)yb)[gid];
  v.x = fmaxf((v.x - mean)*inv*g + be, 0.f);
  v.y = fmaxf((v.y - mean)*inv*g + be, 0.f);
  v.z = fmaxf((v.z - mean)*inv*g + be, 0.f);
  v.w = fmaxf((v.w - mean)*inv*g + be, 0.f);
  ((float4*)yb)[gid] = v;
}

extern "C" void kernel_launch(void* const* d_in, const int* in_sizes, int n_in,
                              void* d_out, int out_size, void* d_ws, size_t ws_size,
                              hipStream_t stream) {
  const float* cen   = (const float*)d_in[0];
  const float* sumw  = (const float*)d_in[1];
  const float* qw    = (const float*)d_in[2];
  const float* kw    = (const float*)d_in[3];
  const float* vw    = (const float*)d_in[4];
  const float* ow    = (const float*)d_in[5];
  const float* gamma = (const float*)d_in[6];
  const float* beta  = (const float*)d_in[7];

  char* ws = (char*)d_ws;
  unsigned short* cenbf  = (unsigned short*)(ws + WS_CENPAD);
  unsigned short* Wb     = (unsigned short*)(ws + WS_W);
  float*          qbuf   = (float*)(ws + WS_Q);
  unsigned short* KV     = (unsigned short*)(ws + WS_KV);
  float*          spart  = (float*)(ws + WS_SPART);
  float*          kkp    = (float*)(ws + WS_KKP);
  float*          qqp    = (float*)(ws + WS_QQP);
  float*          attnT  = (float*)(ws + WS_ATTN);
  float*          outbuf = (float*)(ws + WS_OUT);
  float*          bn     = (float*)(ws + WS_BN);

  pad_kernel    <<<25088, 256, 0, stream>>>(cen, cenbf);
  prep_kernel   <<<2304, 256, 0, stream>>>(sumw, kw, vw, Wb);
  qproj_kernel  <<<dim3(36, 32), 256, 0, stream>>>(cen, qw, qbuf);
  conv_kv_mfma  <<<dim3(36, 1, 32), 512, 0, stream>>>(cenbf, Wb, KV);
  scores_kernel <<<dim3(9, 4, 8), 256, 0, stream>>>(KV, qbuf, spart, kkp, qqp);
  softmax_kernel<<<32, 256, 0, stream>>>(spart, kkp, qqp, attnT);
  pv_kernel     <<<dim3(9, 4, 8), 256, 0, stream>>>(KV, attnT, outbuf);
  outconv_kernel<<<dim3(36, 8), 256, 0, stream>>>(outbuf, ow, (float*)d_out);
  bnstats_kernel<<<64, 256, 0, stream>>>((const float*)d_out, bn);
  bnapply_kernel<<<4608, 256, 0, stream>>>((float*)d_out, bn, gamma, beta);
}